// Round 2
// baseline (139.518 us; speedup 1.0000x reference)
//
#include <hip/hip_runtime.h>

// OccupancyGridForestAS: per-point voxel lookup in a forest of 64 dense 64^3 grids,
// addressed via an 8^3 block->tree lookup table.
//
// Inputs (setup_inputs order):
//   d_in[0]: pts            float32 [4194304, 3]
//   d_in[1]: occ_val_grid   float32 [64, 64, 64, 64]
//   d_in[2]: block_lookup   int32   [8, 8, 8]
// Output: float32 [4194304]
//
// R1 change: gathers are UNCONDITIONAL (invalid lanes read grid[0] -> one
// broadcast transaction per wave) so all 8 gathers per thread are in flight
// simultaneously instead of serialized behind divergent branches.
// 8 points/thread: 6x float4 coalesced loads, 8 independent gathers, 2x float4 store.

#define LDIM 8
#define RES  64
#define PPT  8   // points per thread

__global__ __launch_bounds__(256) void occ_forest_kernel(
    const float4* __restrict__ pts4,
    const float*  __restrict__ grid,
    const int*    __restrict__ lookup,
    float4*       __restrict__ out4,
    int n8)       // number of 8-point groups
{
    int j = blockIdx.x * blockDim.x + threadIdx.x;
    if (j >= n8) return;

    // 8 points = 24 floats = 6 float4s.
    float4 q0 = pts4[6 * j + 0];
    float4 q1 = pts4[6 * j + 1];
    float4 q2 = pts4[6 * j + 2];
    float4 q3 = pts4[6 * j + 3];
    float4 q4 = pts4[6 * j + 4];
    float4 q5 = pts4[6 * j + 5];

    float px[PPT] = {q0.x, q0.w, q1.z, q2.y, q3.x, q3.w, q4.z, q5.y};
    float py[PPT] = {q0.y, q1.x, q1.w, q2.z, q3.y, q4.x, q4.w, q5.z};
    float pz[PPT] = {q0.z, q1.y, q2.x, q2.w, q3.z, q4.y, q5.x, q5.w};

    int   idx[PPT];
    bool  valid[PPT];

    // Phase 1: pure ALU — compute all gather indices (0 for invalid lanes so
    // they coalesce into a single broadcast line hit).
#pragma unroll
    for (int k = 0; k < PPT; ++k) {
        float x = px[k], y = py[k], z = pz[k];

        int bx = (int)floorf(x);
        int by = (int)floorf(y);
        int bz = (int)floorf(z);
        bool in_dom = (bx >= 0) & (bx < LDIM) &
                      (by >= 0) & (by < LDIM) &
                      (bz >= 0) & (bz < LDIM);
        int cx = min(max(bx, 0), LDIM - 1);
        int cy = min(max(by, 0), LDIM - 1);
        int cz = min(max(bz, 0), LDIM - 1);

        int bidx = lookup[(cx * LDIM + cy) * LDIM + cz];  // 2KB table, L1-resident
        bool v = in_dom & (bidx >= 0);

        // Reference float op sequence, replicated exactly:
        // block_x = 2*(p - bcs) - 1 ; t = (block_x*0.5 + 0.5)*res ; vox = clip(floor(t),0,res-1)
        float bxf = 2.0f * (x - (float)cx) - 1.0f;
        float byf = 2.0f * (y - (float)cy) - 1.0f;
        float bzf = 2.0f * (z - (float)cz) - 1.0f;
        float tx = (bxf * 0.5f + 0.5f) * (float)RES;
        float ty = (byf * 0.5f + 0.5f) * (float)RES;
        float tz = (bzf * 0.5f + 0.5f) * (float)RES;
        int vx = min(max((int)floorf(tx), 0), RES - 1);
        int vy = min(max((int)floorf(ty), 0), RES - 1);
        int vz = min(max((int)floorf(tz), 0), RES - 1);

        int sb = v ? bidx : 0;
        int ii = ((sb * RES + vx) * RES + vy) * RES + vz;  // < 2^24
        idx[k]   = v ? ii : 0;   // invalid -> grid[0]: same-line broadcast, ~free
        valid[k] = v;
    }

    // Phase 2: 8 independent unconditional gathers — all in flight at once.
    float vals[PPT];
#pragma unroll
    for (int k = 0; k < PPT; ++k) {
        vals[k] = grid[idx[k]];
    }

    // Phase 3: select + coalesced store.
#pragma unroll
    for (int k = 0; k < PPT; ++k) {
        vals[k] = valid[k] ? vals[k] : 0.0f;
    }

    out4[2 * j + 0] = make_float4(vals[0], vals[1], vals[2], vals[3]);
    out4[2 * j + 1] = make_float4(vals[4], vals[5], vals[6], vals[7]);
}

extern "C" void kernel_launch(void* const* d_in, const int* in_sizes, int n_in,
                              void* d_out, int out_size, void* d_ws, size_t ws_size,
                              hipStream_t stream) {
    const float* pts    = (const float*)d_in[0];
    const float* grid   = (const float*)d_in[1];
    const int*   lookup = (const int*)d_in[2];
    float*       out    = (float*)d_out;

    // out_size = 4194304, divisible by 8; 8 points per thread.
    int n8 = out_size / PPT;                 // 524288 threads
    int threads = 256;
    int blocks = (n8 + threads - 1) / threads;  // 2048 blocks = 2048/CU-pass
    occ_forest_kernel<<<blocks, threads, 0, stream>>>(
        (const float4*)pts, grid, lookup, (float4*)out, n8);
}

// Round 3
// 137.184 us; speedup vs baseline: 1.0170x; 1.0170x over previous
//
#include <hip/hip_runtime.h>

// OccupancyGridForestAS: per-point voxel lookup in a forest of 64 dense 64^3 grids,
// addressed via an 8^3 block->tree lookup table.
//
// Inputs (setup_inputs order):
//   d_in[0]: pts            float32 [4194304, 3]   (48 MiB, streamed)
//   d_in[1]: occ_val_grid   float32 [64, 64, 64, 64] (64 MiB, random 4B gathers)
//   d_in[2]: block_lookup   int32   [8, 8, 8]      (2 KiB)
// Output: float32 [4194304] (16 MiB, streamed)
//
// R2 -> R3 changes:
//  * L3 prefetch: every thread streams 32 floats (8x float4) of the grid at kernel
//    start. All 2048 blocks are co-resident (8/CU x 256 CU), so the whole 64 MiB
//    grid is pulled into the 256 MiB L3 at full BW (~10 us) before/while the random
//    gathers execute -> gathers become L3 hits (~400 cyc) instead of HBM misses
//    (~900 cyc). The harness's 268 MB poison fill thrashes L3 before every launch,
//    so without this the grid is always L3-cold.
//  * block_lookup staged in LDS (512 ints): removes per-point random L1 gather
//    traffic; random over 32 banks is ~2-way aliased = free.

#define LDIM 8
#define RES  64
#define PPT  8   // points per thread

__global__ __launch_bounds__(256) void occ_forest_kernel(
    const float4* __restrict__ pts4,
    const float*  __restrict__ grid,
    const int*    __restrict__ lookup,
    float4*       __restrict__ out4,
    int n8)       // number of 8-point groups (= total threads)
{
    __shared__ int slut[LDIM * LDIM * LDIM];  // 512 ints = 2 KB

    // Stage lookup table into LDS (coalesced int2 loads).
    {
        const int2* lk2 = (const int2*)lookup;
        int2* sl2 = (int2*)slut;
        sl2[threadIdx.x] = lk2[threadIdx.x];  // 256 threads x 8B = 2 KB
    }

    int j = blockIdx.x * blockDim.x + threadIdx.x;

    // --- L3 prefetch of the grid: 8 coalesced float4 loads per thread. ---
    // Total threads (524288) x 32 floats = 16,777,216 floats = whole grid.
    float pf = 0.0f;
    {
        const float4* g4 = (const float4*)grid;
        int base = j;               // stride = total threads in float4 units
        int stride = n8;
#pragma unroll
        for (int s = 0; s < 8; ++s) {
            float4 t = g4[base + s * stride];
            pf += t.x + t.y + t.z + t.w;   // kept alive by asm at the end
        }
    }

    __syncthreads();  // slut ready

    // 8 points = 24 floats = 6 float4s, fully coalesced.
    float4 q0 = pts4[6 * j + 0];
    float4 q1 = pts4[6 * j + 1];
    float4 q2 = pts4[6 * j + 2];
    float4 q3 = pts4[6 * j + 3];
    float4 q4 = pts4[6 * j + 4];
    float4 q5 = pts4[6 * j + 5];

    float px[PPT] = {q0.x, q0.w, q1.z, q2.y, q3.x, q3.w, q4.z, q5.y};
    float py[PPT] = {q0.y, q1.x, q1.w, q2.z, q3.y, q4.x, q4.w, q5.z};
    float pz[PPT] = {q0.z, q1.y, q2.x, q2.w, q3.z, q4.y, q5.x, q5.w};

    int  idx[PPT];
    bool valid[PPT];

    // Phase 1: pure ALU — compute all gather indices (0 for invalid lanes so
    // they coalesce into a single broadcast line hit).
#pragma unroll
    for (int k = 0; k < PPT; ++k) {
        float x = px[k], y = py[k], z = pz[k];

        int bx = (int)floorf(x);
        int by = (int)floorf(y);
        int bz = (int)floorf(z);
        bool in_dom = (bx >= 0) & (bx < LDIM) &
                      (by >= 0) & (by < LDIM) &
                      (bz >= 0) & (bz < LDIM);
        int cx = min(max(bx, 0), LDIM - 1);
        int cy = min(max(by, 0), LDIM - 1);
        int cz = min(max(bz, 0), LDIM - 1);

        int bidx = slut[(cx * LDIM + cy) * LDIM + cz];
        bool v = in_dom & (bidx >= 0);

        // Reference float op sequence, replicated exactly:
        // block_x = 2*(p - bcs) - 1 ; t = (block_x*0.5 + 0.5)*res ; vox = clip(floor(t),0,res-1)
        float bxf = 2.0f * (x - (float)cx) - 1.0f;
        float byf = 2.0f * (y - (float)cy) - 1.0f;
        float bzf = 2.0f * (z - (float)cz) - 1.0f;
        float tx = (bxf * 0.5f + 0.5f) * (float)RES;
        float ty = (byf * 0.5f + 0.5f) * (float)RES;
        float tz = (bzf * 0.5f + 0.5f) * (float)RES;
        int vx = min(max((int)floorf(tx), 0), RES - 1);
        int vy = min(max((int)floorf(ty), 0), RES - 1);
        int vz = min(max((int)floorf(tz), 0), RES - 1);

        int sb = v ? bidx : 0;
        int ii = ((sb * RES + vx) * RES + vy) * RES + vz;  // < 2^24
        idx[k]   = v ? ii : 0;   // invalid -> grid[0]: same-line broadcast, ~free
        valid[k] = v;
    }

    // Phase 2: 8 independent unconditional gathers — all in flight at once.
    float vals[PPT];
#pragma unroll
    for (int k = 0; k < PPT; ++k) {
        vals[k] = grid[idx[k]];
    }

    // Phase 3: select + coalesced store.
#pragma unroll
    for (int k = 0; k < PPT; ++k) {
        vals[k] = valid[k] ? vals[k] : 0.0f;
    }

    out4[2 * j + 0] = make_float4(vals[0], vals[1], vals[2], vals[3]);
    out4[2 * j + 1] = make_float4(vals[4], vals[5], vals[6], vals[7]);

    // Keep the prefetch accumulator alive without touching the output.
    asm volatile("" :: "v"(pf));
}

extern "C" void kernel_launch(void* const* d_in, const int* in_sizes, int n_in,
                              void* d_out, int out_size, void* d_ws, size_t ws_size,
                              hipStream_t stream) {
    const float* pts    = (const float*)d_in[0];
    const float* grid   = (const float*)d_in[1];
    const int*   lookup = (const int*)d_in[2];
    float*       out    = (float*)d_out;

    // out_size = 4194304, divisible by 8; 8 points per thread.
    int n8 = out_size / PPT;                    // 524288 threads
    int threads = 256;
    int blocks = (n8 + threads - 1) / threads;  // 2048 blocks = 8/CU, all co-resident
    occ_forest_kernel<<<blocks, threads, 0, stream>>>(
        (const float4*)pts, grid, lookup, (float4*)out, n8);
}